// Round 7
// baseline (159.775 us; speedup 1.0000x reference)
//
#include <hip/hip_runtime.h>

typedef _Float16 half8 __attribute__((ext_vector_type(8)));
typedef float floatx4 __attribute__((ext_vector_type(4)));

#define SEQ 2048
#define DMODEL 1024
#define NHEADS 16
#define HEADDIM 64
#define PW 5120   // proj row width: q|k|v|kg|vg

// ---------------- fused prep: x fp32->fp16 + 6 weight transposes ----------------
__global__ __launch_bounds__(256) void k_prep(
    const float* __restrict__ x,
    const float* __restrict__ w0, const float* __restrict__ w1, const float* __restrict__ w2,
    const float* __restrict__ w3, const float* __restrict__ w4, const float* __restrict__ w5,
    _Float16* __restrict__ xh, _Float16* __restrict__ wcat, _Float16* __restrict__ wot) {
  const int tid = threadIdx.x;
  const int b = blockIdx.x;
  if (b < 1024) {
    int base = b * 2048 + tid * 8;
    floatx4 f0 = *(const floatx4*)(x + base);
    floatx4 f1 = *(const floatx4*)(x + base + 4);
    half8 h;
    #pragma unroll
    for (int e = 0; e < 4; ++e) { h[e] = (_Float16)f0[e]; h[e + 4] = (_Float16)f1[e]; }
    *(half8*)(xh + base) = h;
    return;
  }
  __shared__ _Float16 T[64][72];
  int t = b - 1024;
  int z = t >> 8;
  int tile = t & 255;
  int k0 = (tile >> 4) * 64, n0 = (tile & 15) * 64;
  const float* W = (z == 0) ? w0 : (z == 1) ? w1 : (z == 2) ? w2
                 : (z == 3) ? w3 : (z == 4) ? w4 : w5;
  _Float16* dst = (z < 5) ? (wcat + (size_t)z * 1024 * 1024) : wot;

  int lr = tid >> 2, c0 = (tid & 3) * 16;
  #pragma unroll
  for (int i = 0; i < 4; ++i) {
    floatx4 f = *(const floatx4*)(W + (size_t)(k0 + lr) * DMODEL + n0 + c0 + i * 4);
    #pragma unroll
    for (int e = 0; e < 4; ++e) T[c0 + i * 4 + e][lr] = (_Float16)f[e];
  }
  __syncthreads();
  int nr = tid >> 2, s0 = (tid & 3) * 16;
  #pragma unroll
  for (int i = 0; i < 2; ++i) {
    half8 h = *(const half8*)&T[nr][s0 + i * 8];
    *(half8*)(dst + (size_t)(n0 + nr) * DMODEL + k0 + s0 + i * 8) = h;
  }
}

// ------------- BMxBN MFMA GEMM, BK=128 1-phase, global_load_lds + XOR swizzle -------------
// R3/R5 structure (best measured): single-buffered, __syncthreads-delimited K-steps;
// latency hiding comes from multi-block co-residency, not source pipelining.
// XCD-aware blockIdx swizzle (T1) on both grids — consecutive work items
// (n-major, shared B-tile) land on the SAME XCD's L2 instead of round-robin.
// BM=128,BN=64 (proj): wave grid 4x1, acc[2][4]; RoPE pairs (d,d+32) intra-wave.
//   48KB LDS -> 3 blocks/CU. Grid 800 = 8*100 (bijective swizzle).
// BM=64,BN=64 (out): 1D grid 512 = 8*64, n-major; wave grid 2x2, acc[2][2]; 32KB.
template <bool HALF_OUT, bool FUSE_ROPE, bool SPARSE, int BM, int BN>
__global__ __launch_bounds__(256, 3) void k_gemm(
    const _Float16* __restrict__ A, const _Float16* __restrict__ Bt,
    void* __restrict__ Cv, float* __restrict__ Cp,
    const float* __restrict__ cos_t, const float* __restrict__ sin_t,
    const int* __restrict__ pos, int M, int N, int K) {
  __shared__ _Float16 As[BM][128];
  __shared__ _Float16 Bs[BN][128];
  const int tid = threadIdx.x;
  const int lane = tid & 63;
  const int w = tid >> 6;
  const int l15 = lane & 15;
  const int q4 = lane >> 4;
  constexpr int NJ = (BM == 128) ? 4 : 2;           // col fragments per wave
  const int wm = (BM == 128) ? w * 32 : (w >> 1) * 32;
  const int wn = (BM == 128) ? 0 : (w & 1) * 32;
  int m0, n0;
  if (SPARSE) {
    int b = blockIdx.x;
    b = (b & 7) * 100 + (b >> 3);        // XCD swizzle: 800 = 8*100, bijective
    if (b < 768) { m0 = (b & 15) * 128; n0 = (b >> 4) * 64; }
    else         { m0 = 0;              n0 = 3072 + (b - 768) * 64; }
  } else {
    int b = blockIdx.x;
    b = (b & 7) * 64 + (b >> 3);         // XCD swizzle: 512 = 8*64, bijective
    m0 = (b & 31) * BM;                  // n-major: consecutive b share n0 (B-tile)
    n0 = (b >> 5) * BN;
  }

  floatx4 acc[2][NJ];
  #pragma unroll
  for (int i = 0; i < 2; ++i)
    #pragma unroll
    for (int j = 0; j < NJ; ++j) acc[i][j] = (floatx4){0.f, 0.f, 0.f, 0.f};

  _Float16* asBase = &As[0][0];
  _Float16* bsBase = &Bs[0][0];
  const int swz = l15 & 7;

  for (int k0 = 0; k0 < K; k0 += 128) {
    __syncthreads();
    #pragma unroll
    for (int it = 0; it < BM / 16; ++it) {
      int c = it * 256 + tid;          // A: 16B chunks, 16 chunks/row
      int r = c >> 4, cc = c & 15;
      int g = cc ^ (r & 7);            // swizzled global k-chunk
      __builtin_amdgcn_global_load_lds(
          (const __attribute__((address_space(1))) void*)(A + (size_t)(m0 + r) * K + k0 + g * 8),
          (__attribute__((address_space(3))) void*)(asBase + (it * 256 + w * 64) * 8),
          16, 0, 0);
    }
    #pragma unroll
    for (int it = 0; it < BN / 16; ++it) {
      int c = it * 256 + tid;          // B: 16B chunks
      int r = c >> 4, cc = c & 15;
      int g = cc ^ (r & 7);
      __builtin_amdgcn_global_load_lds(
          (const __attribute__((address_space(1))) void*)(Bt + (size_t)(n0 + r) * K + k0 + g * 8),
          (__attribute__((address_space(3))) void*)(bsBase + (it * 256 + w * 64) * 8),
          16, 0, 0);
    }
    __syncthreads();

    #pragma unroll
    for (int kk = 0; kk < 4; ++kk) {
      int q = kk * 4 + q4;             // global k-chunk 0..15
      half8 af[2], bf[NJ];
      #pragma unroll
      for (int t = 0; t < 2; ++t) {
        int ar = wm + t * 16 + l15;
        af[t] = *(const half8*)(asBase + (size_t)ar * 128 + ((q ^ swz) * 8));
      }
      #pragma unroll
      for (int t = 0; t < NJ; ++t) {
        int br = wn + t * 16 + l15;
        bf[t] = *(const half8*)(bsBase + (size_t)br * 128 + ((q ^ swz) * 8));
      }
      #pragma unroll
      for (int i = 0; i < 2; ++i)
        #pragma unroll
        for (int j = 0; j < NJ; ++j)
          acc[i][j] = __builtin_amdgcn_mfma_f32_16x16x32_f16(af[i], bf[j], acc[i][j], 0, 0, 0);
    }
  }

  #pragma unroll
  for (int tm = 0; tm < 2; ++tm) {
    #pragma unroll
    for (int r = 0; r < 4; ++r) {
      int row = m0 + wm + tm * 16 + q4 * 4 + r;
      float v[NJ];
      #pragma unroll
      for (int tn = 0; tn < NJ; ++tn) v[tn] = acc[tm][tn][r];
      if (FUSE_ROPE && NJ == 4 && n0 < 2048) {
        int p = pos[row];
        #pragma unroll
        for (int tn = 0; tn < 2; ++tn) {
          int d = tn * 16 + l15;       // head-local col (wave spans full head)
          float a = acc[tm][tn][r];
          float bvv = acc[tm][tn + 2][r];
          float c1 = cos_t[p * 64 + d],      s1 = sin_t[p * 64 + d];
          float c2 = cos_t[p * 64 + d + 32], s2 = sin_t[p * 64 + d + 32];
          v[tn]     = a * c1 - bvv * s1;
          v[tn + 2] = bvv * c2 + a * s2;
        }
      }
      #pragma unroll
      for (int tn = 0; tn < NJ; ++tn) {
        int col = n0 + wn + tn * 16 + l15;
        if (HALF_OUT)
          ((_Float16*)Cv)[(size_t)row * N + col] = (_Float16)v[tn];
        else
          Cp[(size_t)row * N + col] = v[tn];
      }
    }
  }
}

// ---------------- merged attention: BM=32 flash tiles (128-thr) + early rows ----------------
// Fixed softmax reference m == 0 (scores O(+-3); shift invariance -> exact), linear
// l-sum deferred to epilogue. T14 reg staging; Vtc XOR swizzle (col ^ (d&56)).
// BM=32 / 2-wave blocks: per-wave work per chunk is IDENTICAL to BM=64 (16 rows/wave)
// but heavy-block count doubles to 896 -> 3.5 blocks/CU resident (vs 1.75): the
// serial chunk chain of one block hides under 2-3 co-resident peers. LDS ~29KB.
__global__ __launch_bounds__(128, 2) void k_attn(const _Float16* __restrict__ proj,
                                                 _Float16* __restrict__ out) {
  const int tid = threadIdx.x;
  const int hb = blockIdx.y * 64;

  if (blockIdx.x >= 56) {
    // ---- early rows 0..259 (absorbed-1e9: uniform avg over in-window global cols) ----
    const int i = (blockIdx.x - 56) * 2 + (tid >> 6);
    const int lane = tid & 63;
    const float scale = 0.125f;
    float qv = (float)proj[(size_t)i * PW + hb + lane];
    float sg[4];
    #pragma unroll
    for (int g = 0; g < 4; ++g) {
      float kgv = (float)proj[(size_t)g * PW + 3072 + hb + lane];
      float v = qv * kgv;
      #pragma unroll
      for (int off = 32; off; off >>= 1) v += __shfl_xor(v, off, 64);
      sg[g] = v * scale;
    }
    float mg = fmaxf(fmaxf(sg[0], sg[1]), fmaxf(sg[2], sg[3]));
    float dg = 0.f, og = 0.f;
    #pragma unroll
    for (int g = 0; g < 4; ++g) {
      float p = __expf(sg[g] - mg);
      dg += p;
      og += p * (float)proj[(size_t)g * PW + 4096 + hb + lane];
    }
    og /= dg;
    int jmin = (i >= 256) ? (i - 256) : 0;
    int jmax = (i < 3) ? i : 3;
    float acc = 0.f;
    for (int j = jmin; j <= jmax; ++j)
      acc += (float)proj[(size_t)j * PW + 2048 + hb + lane];
    float ol = acc / (float)(jmax - jmin + 1);
    out[(size_t)i * DMODEL + hb + lane] = (_Float16)(ol + og);
    return;
  }

  // ---- flash path: 32 Q-rows per block (2 waves x 16 rows), 5 chunks of 64 cols ----
  const int i0 = 256 + blockIdx.x * 32;
  const int jlo = i0 - 256;
  const int lane = tid & 63;
  const int w = tid >> 6;          // 0..1
  const int l15 = lane & 15;
  const int q4 = lane >> 4;

  __shared__ _Float16 Qs[32][72];
  __shared__ _Float16 Kc[64][72];
  __shared__ _Float16 Vtc[64][72];
  __shared__ _Float16 Ps[32][72];
  __shared__ _Float16 kg_s[4][64];
  __shared__ _Float16 vg_s[4][64];
  __shared__ float svg_s[64];
  __shared__ float pg_s[4][32];

  #pragma unroll
  for (int rep = 0; rep < 2; ++rep) {
    int c = tid + rep * 128;
    int r = c >> 3, q = c & 7;     // 32 rows x 8 chunks
    *(half8*)&Qs[r][q * 8] = *(const half8*)(proj + (size_t)(i0 + r) * PW + hb + q * 8);
  }
  #pragma unroll
  for (int rep = 0; rep < 2; ++rep) {
    int idx = tid + rep * 128;
    int g = idx >> 6, c2 = idx & 63;
    kg_s[g][c2] = proj[(size_t)g * PW + 3072 + hb + c2];
    vg_s[g][c2] = proj[(size_t)g * PW + 4096 + hb + c2];
  }
  if (tid < 64) {
    float s = 0.f;
    #pragma unroll
    for (int g2 = 0; g2 < 4; ++g2) s += (float)proj[(size_t)g2 * PW + 2048 + hb + tid];
    svg_s[tid] = s;
  }
  __syncthreads();

  // global-attn probs for the 32 rows: (w, lane>>2) -> row, lane&3 -> k-part
  {
    int ro = w * 16 + (lane >> 2);
    int part = lane & 3;
    float sg[4];
    #pragma unroll
    for (int g = 0; g < 4; ++g) {
      float acc = 0.f;
      #pragma unroll
      for (int u = 0; u < 16; ++u)
        acc += (float)Qs[ro][part * 16 + u] * (float)kg_s[g][part * 16 + u];
      acc += __shfl_xor(acc, 1, 64);
      acc += __shfl_xor(acc, 2, 64);
      sg[g] = acc * 0.125f;
    }
    float mg = fmaxf(fmaxf(sg[0], sg[1]), fmaxf(sg[2], sg[3]));
    float dg = 0.f;
    #pragma unroll
    for (int g = 0; g < 4; ++g) dg += __expf(sg[g] - mg);
    pg_s[part][ro] = __expf(sg[part] - mg) / dg;
  }

  half8 qf0 = *(const half8*)&Qs[w * 16 + l15][q4 * 8];
  half8 qf1 = *(const half8*)&Qs[w * 16 + l15][32 + q4 * 8];

  float lpart[4];
  floatx4 oacc[4];
  #pragma unroll
  for (int cb = 0; cb < 4; ++cb) {
    oacc[cb] = (floatx4){0.f, 0.f, 0.f, 0.f};
    lpart[cb] = 0.f;
  }

  // staging indices (128 threads, 4 slots each; all indices compile-time unrolled)
  const int krr = tid >> 3, krq = tid & 7;          // K row base / col chunk
  const int vjb = (tid & 7) + ((tid >> 6) << 3);    // V j base (0..15)
  const int vd0 = ((tid >> 3) & 7) * 8;             // V d chunk

  half8 kr[4], vr[4];
  {
    const _Float16* kb = proj + (size_t)jlo * PW + 1024 + hb;
    const _Float16* vb = proj + (size_t)jlo * PW + 2048 + hb;
    #pragma unroll
    for (int it = 0; it < 4; ++it) {
      kr[it] = *(const half8*)(kb + (size_t)(krr + it * 16) * PW + krq * 8);
      vr[it] = *(const half8*)(vb + (size_t)(vjb + it * 16) * PW + vd0);
    }
  }

  for (int cc = 0; cc < 5; ++cc) {
    __syncthreads();
    #pragma unroll
    for (int it = 0; it < 4; ++it) {
      *(half8*)&Kc[krr + it * 16][krq * 8] = kr[it];
      #pragma unroll
      for (int u = 0; u < 8; ++u) {
        int d = vd0 + u;
        Vtc[d][(vjb + it * 16) ^ (d & 56)] = vr[it][u];
      }
    }
    if (cc < 4) {
      const _Float16* kb = proj + (size_t)(jlo + (cc + 1) * 64) * PW + 1024 + hb;
      const _Float16* vb = proj + (size_t)(jlo + (cc + 1) * 64) * PW + 2048 + hb;
      #pragma unroll
      for (int it = 0; it < 4; ++it) {
        kr[it] = *(const half8*)(kb + (size_t)(krr + it * 16) * PW + krq * 8);
        vr[it] = *(const half8*)(vb + (size_t)(vjb + it * 16) * PW + vd0);
      }
    }
    __syncthreads();

    float sc[4][4];
    #pragma unroll
    for (int cb = 0; cb < 4; ++cb) {
      half8 b0 = *(const half8*)&Kc[cb * 16 + l15][q4 * 8];
      half8 b1 = *(const half8*)&Kc[cb * 16 + l15][32 + q4 * 8];
      floatx4 a = (floatx4){0.f, 0.f, 0.f, 0.f};
      a = __builtin_amdgcn_mfma_f32_16x16x32_f16(qf0, b0, a, 0, 0, 0);
      a = __builtin_amdgcn_mfma_f32_16x16x32_f16(qf1, b1, a, 0, 0, 0);
      #pragma unroll
      for (int r = 0; r < 4; ++r) sc[cb][r] = a[r];
    }

    #pragma unroll
    for (int r = 0; r < 4; ++r) {
      int ri = w * 16 + q4 * 4 + r;
      float rowp = 0.f;
      #pragma unroll
      for (int cb = 0; cb < 4; ++cb) {
        int jjg = cc * 64 + cb * 16 + l15;
        bool valid = (jjg >= ri) && (jjg <= ri + 256);
        float p = valid ? __expf(sc[cb][r] * 0.125f) : 0.f;
        Ps[ri][cb * 16 + l15] = (_Float16)p;
        rowp += p;
      }
      lpart[r] += rowp;
    }

    half8 pf0 = *(const half8*)&Ps[w * 16 + l15][q4 * 8];
    half8 pf1 = *(const half8*)&Ps[w * 16 + l15][32 + q4 * 8];
    #pragma unroll
    for (int cb = 0; cb < 4; ++cb) {
      int dv = cb * 16 + l15;
      half8 v0 = *(const half8*)&Vtc[dv][(q4 * 8) ^ (dv & 56)];
      half8 v1 = *(const half8*)&Vtc[dv][(32 + q4 * 8) ^ (dv & 56)];
      oacc[cb] = __builtin_amdgcn_mfma_f32_16x16x32_f16(pf0, v0, oacc[cb], 0, 0, 0);
      oacc[cb] = __builtin_amdgcn_mfma_f32_16x16x32_f16(pf1, v1, oacc[cb], 0, 0, 0);
    }
  }

  #pragma unroll
  for (int r = 0; r < 4; ++r) {
    int ri = w * 16 + q4 * 4 + r;
    if (i0 + ri < 260) continue;
    float lsum = lpart[r];
    #pragma unroll
    for (int off = 1; off < 16; off <<= 1) lsum += __shfl_xor(lsum, off, 64);
    float inv = 1.f / (lsum + 4.f);   // +4: global cols 0..3 at score exactly 0
    #pragma unroll
    for (int cb = 0; cb < 4; ++cb) {
      int col = cb * 16 + l15;
      float ol = (oacc[cb][r] + svg_s[col]) * inv;
      float og = 0.f;
      #pragma unroll
      for (int g = 0; g < 4; ++g) og += pg_s[g][ri] * (float)vg_s[g][col];
      out[(size_t)(i0 + ri) * DMODEL + hb + col] = (_Float16)(ol + og);
    }
  }
}

// ---------------- launcher ----------------
extern "C" void kernel_launch(void* const* d_in, const int* in_sizes, int n_in,
                              void* d_out, int out_size, void* d_ws, size_t ws_size,
                              hipStream_t stream) {
  const float* x     = (const float*)d_in[0];
  const float* cos_t = (const float*)d_in[1];
  const float* sin_t = (const float*)d_in[2];
  const int*   pos   = (const int*)d_in[3];
  const float* Wqs   = (const float*)d_in[4];
  const float* Wks   = (const float*)d_in[5];
  const float* Wvs   = (const float*)d_in[6];
  const float* Wkg   = (const float*)d_in[8];
  const float* Wvg   = (const float*)d_in[9];
  const float* Wo    = (const float*)d_in[10];
  float* out = (float*)d_out;

  char* ws = (char*)d_ws;
  _Float16* xh   = (_Float16*)(ws);                 //  4 MB
  _Float16* wcat = (_Float16*)(ws + (4u << 20));    // 10 MB
  _Float16* wot  = (_Float16*)(ws + (14u << 20));   //  2 MB
  _Float16* proj = (_Float16*)(ws + (16u << 20));   // 20 MB
  _Float16* attn = (_Float16*)(ws + (36u << 20));   //  4 MB

  k_prep<<<2560, 256, 0, stream>>>(x, Wqs, Wks, Wvs, Wkg, Wvg, Wo, xh, wcat, wot);
  // sparse proj GEMM: 768 blocks q|k|v (all M) + 32 blocks kg|vg (m0=0 only), XCD-swizzled
  k_gemm<true, true, true, 128, 64><<<800, 256, 0, stream>>>(
      xh, wcat, proj, nullptr, cos_t, sin_t, pos, SEQ, PW, DMODEL);
  // attn: 56 flash tiles (32 rows) + 130 early blocks (2 rows), per head; 128 threads
  k_attn<<<dim3(186, NHEADS), 128, 0, stream>>>(proj, attn);
  // out GEMM: 64x64 tiles, 1D grid 512 (XCD-swizzled, n-major), fp32 direct to out
  k_gemm<false, false, false, 64, 64><<<512, 256, 0, stream>>>(
      attn, wot, nullptr, out, cos_t, sin_t, pos, SEQ, DMODEL, DMODEL);
}

// Round 8
// 157.222 us; speedup vs baseline: 1.0162x; 1.0162x over previous
//
#include <hip/hip_runtime.h>

typedef _Float16 half8 __attribute__((ext_vector_type(8)));
typedef float floatx4 __attribute__((ext_vector_type(4)));

#define SEQ 2048
#define DMODEL 1024
#define NHEADS 16
#define HEADDIM 64
#define PW 5120   // proj row width: q|k|v|kg|vg

// ---------------- fused prep: x fp32->fp16 + 6 weight transposes ----------------
__global__ __launch_bounds__(256) void k_prep(
    const float* __restrict__ x,
    const float* __restrict__ w0, const float* __restrict__ w1, const float* __restrict__ w2,
    const float* __restrict__ w3, const float* __restrict__ w4, const float* __restrict__ w5,
    _Float16* __restrict__ xh, _Float16* __restrict__ wcat, _Float16* __restrict__ wot) {
  const int tid = threadIdx.x;
  const int b = blockIdx.x;
  if (b < 1024) {
    int base = b * 2048 + tid * 8;
    floatx4 f0 = *(const floatx4*)(x + base);
    floatx4 f1 = *(const floatx4*)(x + base + 4);
    half8 h;
    #pragma unroll
    for (int e = 0; e < 4; ++e) { h[e] = (_Float16)f0[e]; h[e + 4] = (_Float16)f1[e]; }
    *(half8*)(xh + base) = h;
    return;
  }
  __shared__ _Float16 T[64][72];
  int t = b - 1024;
  int z = t >> 8;
  int tile = t & 255;
  int k0 = (tile >> 4) * 64, n0 = (tile & 15) * 64;
  const float* W = (z == 0) ? w0 : (z == 1) ? w1 : (z == 2) ? w2
                 : (z == 3) ? w3 : (z == 4) ? w4 : w5;
  _Float16* dst = (z < 5) ? (wcat + (size_t)z * 1024 * 1024) : wot;

  int lr = tid >> 2, c0 = (tid & 3) * 16;
  #pragma unroll
  for (int i = 0; i < 4; ++i) {
    floatx4 f = *(const floatx4*)(W + (size_t)(k0 + lr) * DMODEL + n0 + c0 + i * 4);
    #pragma unroll
    for (int e = 0; e < 4; ++e) T[c0 + i * 4 + e][lr] = (_Float16)f[e];
  }
  __syncthreads();
  int nr = tid >> 2, s0 = (tid & 3) * 16;
  #pragma unroll
  for (int i = 0; i < 2; ++i) {
    half8 h = *(const half8*)&T[nr][s0 + i * 8];
    *(half8*)(dst + (size_t)(n0 + nr) * DMODEL + k0 + s0 + i * 8) = h;
  }
}

// ------------- BMxBN MFMA GEMM, BK=128 1-phase, global_load_lds + XOR swizzle -------------
// R3/R5 structure (best measured): single-buffered, __syncthreads-delimited K-steps;
// latency hiding comes from multi-block co-residency, not source pipelining.
// XCD-aware blockIdx swizzle (T1) on both grids — consecutive work items
// (n-major, shared B-tile) land on the SAME XCD's L2 instead of round-robin.
// BM=128,BN=64 (proj): wave grid 4x1, acc[2][4]; RoPE pairs (d,d+32) intra-wave.
//   48KB LDS -> 3 blocks/CU. Grid 800 = 8*100 (bijective swizzle).
// BM=64,BN=64 (out): 1D grid 512 = 8*64, n-major; wave grid 2x2, acc[2][2]; 32KB.
template <bool HALF_OUT, bool FUSE_ROPE, bool SPARSE, int BM, int BN>
__global__ __launch_bounds__(256, 3) void k_gemm(
    const _Float16* __restrict__ A, const _Float16* __restrict__ Bt,
    void* __restrict__ Cv, float* __restrict__ Cp,
    const float* __restrict__ cos_t, const float* __restrict__ sin_t,
    const int* __restrict__ pos, int M, int N, int K) {
  __shared__ _Float16 As[BM][128];
  __shared__ _Float16 Bs[BN][128];
  const int tid = threadIdx.x;
  const int lane = tid & 63;
  const int w = tid >> 6;
  const int l15 = lane & 15;
  const int q4 = lane >> 4;
  constexpr int NJ = (BM == 128) ? 4 : 2;           // col fragments per wave
  const int wm = (BM == 128) ? w * 32 : (w >> 1) * 32;
  const int wn = (BM == 128) ? 0 : (w & 1) * 32;
  int m0, n0;
  if (SPARSE) {
    int b = blockIdx.x;
    b = (b & 7) * 100 + (b >> 3);        // XCD swizzle: 800 = 8*100, bijective
    if (b < 768) { m0 = (b & 15) * 128; n0 = (b >> 4) * 64; }
    else         { m0 = 0;              n0 = 3072 + (b - 768) * 64; }
  } else {
    int b = blockIdx.x;
    b = (b & 7) * 64 + (b >> 3);         // XCD swizzle: 512 = 8*64, bijective
    m0 = (b & 31) * BM;                  // n-major: consecutive b share n0 (B-tile)
    n0 = (b >> 5) * BN;
  }

  floatx4 acc[2][NJ];
  #pragma unroll
  for (int i = 0; i < 2; ++i)
    #pragma unroll
    for (int j = 0; j < NJ; ++j) acc[i][j] = (floatx4){0.f, 0.f, 0.f, 0.f};

  _Float16* asBase = &As[0][0];
  _Float16* bsBase = &Bs[0][0];
  const int swz = l15 & 7;

  for (int k0 = 0; k0 < K; k0 += 128) {
    __syncthreads();
    #pragma unroll
    for (int it = 0; it < BM / 16; ++it) {
      int c = it * 256 + tid;          // A: 16B chunks, 16 chunks/row
      int r = c >> 4, cc = c & 15;
      int g = cc ^ (r & 7);            // swizzled global k-chunk
      __builtin_amdgcn_global_load_lds(
          (const __attribute__((address_space(1))) void*)(A + (size_t)(m0 + r) * K + k0 + g * 8),
          (__attribute__((address_space(3))) void*)(asBase + (it * 256 + w * 64) * 8),
          16, 0, 0);
    }
    #pragma unroll
    for (int it = 0; it < BN / 16; ++it) {
      int c = it * 256 + tid;          // B: 16B chunks
      int r = c >> 4, cc = c & 15;
      int g = cc ^ (r & 7);
      __builtin_amdgcn_global_load_lds(
          (const __attribute__((address_space(1))) void*)(Bt + (size_t)(n0 + r) * K + k0 + g * 8),
          (__attribute__((address_space(3))) void*)(bsBase + (it * 256 + w * 64) * 8),
          16, 0, 0);
    }
    __syncthreads();

    #pragma unroll
    for (int kk = 0; kk < 4; ++kk) {
      int q = kk * 4 + q4;             // global k-chunk 0..15
      half8 af[2], bf[NJ];
      #pragma unroll
      for (int t = 0; t < 2; ++t) {
        int ar = wm + t * 16 + l15;
        af[t] = *(const half8*)(asBase + (size_t)ar * 128 + ((q ^ swz) * 8));
      }
      #pragma unroll
      for (int t = 0; t < NJ; ++t) {
        int br = wn + t * 16 + l15;
        bf[t] = *(const half8*)(bsBase + (size_t)br * 128 + ((q ^ swz) * 8));
      }
      #pragma unroll
      for (int i = 0; i < 2; ++i)
        #pragma unroll
        for (int j = 0; j < NJ; ++j)
          acc[i][j] = __builtin_amdgcn_mfma_f32_16x16x32_f16(af[i], bf[j], acc[i][j], 0, 0, 0);
    }
  }

  #pragma unroll
  for (int tm = 0; tm < 2; ++tm) {
    #pragma unroll
    for (int r = 0; r < 4; ++r) {
      int row = m0 + wm + tm * 16 + q4 * 4 + r;
      float v[NJ];
      #pragma unroll
      for (int tn = 0; tn < NJ; ++tn) v[tn] = acc[tm][tn][r];
      if (FUSE_ROPE && NJ == 4 && n0 < 2048) {
        int p = pos[row];
        #pragma unroll
        for (int tn = 0; tn < 2; ++tn) {
          int d = tn * 16 + l15;       // head-local col (wave spans full head)
          float a = acc[tm][tn][r];
          float bvv = acc[tm][tn + 2][r];
          float c1 = cos_t[p * 64 + d],      s1 = sin_t[p * 64 + d];
          float c2 = cos_t[p * 64 + d + 32], s2 = sin_t[p * 64 + d + 32];
          v[tn]     = a * c1 - bvv * s1;
          v[tn + 2] = bvv * c2 + a * s2;
        }
      }
      #pragma unroll
      for (int tn = 0; tn < NJ; ++tn) {
        int col = n0 + wn + tn * 16 + l15;
        if (HALF_OUT)
          ((_Float16*)Cv)[(size_t)row * N + col] = (_Float16)v[tn];
        else
          Cp[(size_t)row * N + col] = v[tn];
      }
    }
  }
}

// ---------------- merged attention: BM=64 flash tiles + early rows (R5 version) ----------------
// Fixed softmax reference m == 0 (scores O(+-3); shift invariance -> exact), linear
// l-sum deferred to epilogue. T14 reg staging; Vtc XOR swizzle (col ^ (d&56)).
// BM=64/4-wave blocks (R7's BM=32 regressed: same 7 waves/CU but 2x staging traffic).
__global__ __launch_bounds__(256, 2) void k_attn(const _Float16* __restrict__ proj,
                                                 _Float16* __restrict__ out) {
  const int tid = threadIdx.x;
  const int hb = blockIdx.y * 64;

  if (blockIdx.x >= 28) {
    // ---- early rows (absorbed-1e9: uniform average over in-window global cols) ----
    const int i = (blockIdx.x - 28) * 4 + (tid >> 6);
    const int lane = tid & 63;
    const float scale = 0.125f;
    float qv = (float)proj[(size_t)i * PW + hb + lane];
    float sg[4];
    #pragma unroll
    for (int g = 0; g < 4; ++g) {
      float kgv = (float)proj[(size_t)g * PW + 3072 + hb + lane];
      float v = qv * kgv;
      #pragma unroll
      for (int off = 32; off; off >>= 1) v += __shfl_xor(v, off, 64);
      sg[g] = v * scale;
    }
    float mg = fmaxf(fmaxf(sg[0], sg[1]), fmaxf(sg[2], sg[3]));
    float dg = 0.f, og = 0.f;
    #pragma unroll
    for (int g = 0; g < 4; ++g) {
      float p = __expf(sg[g] - mg);
      dg += p;
      og += p * (float)proj[(size_t)g * PW + 4096 + hb + lane];
    }
    og /= dg;
    int jmin = (i >= 256) ? (i - 256) : 0;
    int jmax = (i < 3) ? i : 3;
    float acc = 0.f;
    for (int j = jmin; j <= jmax; ++j)
      acc += (float)proj[(size_t)j * PW + 2048 + hb + lane];
    float ol = acc / (float)(jmax - jmin + 1);
    out[(size_t)i * DMODEL + hb + lane] = (_Float16)(ol + og);
    return;
  }

  // ---- flash path: 64 Q-rows per block, 5 chunks of 64 cols ----
  const int i0 = 256 + blockIdx.x * 64;
  const int jlo = i0 - 256;
  const int lane = tid & 63;
  const int w = tid >> 6;
  const int l15 = lane & 15;
  const int q4 = lane >> 4;

  __shared__ _Float16 Qs[64][72];
  __shared__ _Float16 Kc[64][72];
  __shared__ _Float16 Vtc[64][72];
  __shared__ _Float16 Ps[64][72];
  __shared__ _Float16 kg_s[4][64];
  __shared__ _Float16 vg_s[4][64];
  __shared__ float svg_s[64];
  __shared__ float pg_s[4][64];

  #pragma unroll
  for (int rep = 0; rep < 2; ++rep) {
    int c = tid + rep * 256;
    int r = c >> 3, q = c & 7;
    *(half8*)&Qs[r][q * 8] = *(const half8*)(proj + (size_t)(i0 + r) * PW + hb + q * 8);
  }
  {
    int g = tid >> 6, c2 = tid & 63;
    kg_s[g][c2] = proj[(size_t)g * PW + 3072 + hb + c2];
    vg_s[g][c2] = proj[(size_t)g * PW + 4096 + hb + c2];
    if (tid < 64) {
      float s = 0.f;
      #pragma unroll
      for (int g2 = 0; g2 < 4; ++g2) s += (float)proj[(size_t)g2 * PW + 2048 + hb + tid];
      svg_s[tid] = s;
    }
  }
  __syncthreads();

  // global-attn probs for the 64 rows: (w, lane>>2) -> row, lane&3 -> k-part
  {
    int ro = w * 16 + (lane >> 2);
    int part = lane & 3;
    float sg[4];
    #pragma unroll
    for (int g = 0; g < 4; ++g) {
      float acc = 0.f;
      #pragma unroll
      for (int u = 0; u < 16; ++u)
        acc += (float)Qs[ro][part * 16 + u] * (float)kg_s[g][part * 16 + u];
      acc += __shfl_xor(acc, 1, 64);
      acc += __shfl_xor(acc, 2, 64);
      sg[g] = acc * 0.125f;
    }
    float mg = fmaxf(fmaxf(sg[0], sg[1]), fmaxf(sg[2], sg[3]));
    float dg = 0.f;
    #pragma unroll
    for (int g = 0; g < 4; ++g) dg += __expf(sg[g] - mg);
    pg_s[part][ro] = __expf(sg[part] - mg) / dg;
  }

  half8 qf0 = *(const half8*)&Qs[w * 16 + l15][q4 * 8];
  half8 qf1 = *(const half8*)&Qs[w * 16 + l15][32 + q4 * 8];

  float lpart[4];
  floatx4 oacc[4];
  #pragma unroll
  for (int cb = 0; cb < 4; ++cb) {
    oacc[cb] = (floatx4){0.f, 0.f, 0.f, 0.f};
    lpart[cb] = 0.f;
  }

  const int kr_r0 = tid >> 3, kr_q = tid & 7;
  const int kr_r1 = kr_r0 + 32;
  const int vj0 = (tid & 7) + ((tid >> 6) << 3);
  const int vj1 = vj0 + 32;
  const int vd0 = ((tid >> 3) & 7) * 8;

  half8 kr0, kr1, vr0, vr1;
  {
    const _Float16* kb = proj + (size_t)jlo * PW + 1024 + hb;
    const _Float16* vb = proj + (size_t)jlo * PW + 2048 + hb;
    kr0 = *(const half8*)(kb + (size_t)kr_r0 * PW + kr_q * 8);
    kr1 = *(const half8*)(kb + (size_t)kr_r1 * PW + kr_q * 8);
    vr0 = *(const half8*)(vb + (size_t)vj0 * PW + vd0);
    vr1 = *(const half8*)(vb + (size_t)vj1 * PW + vd0);
  }

  for (int cc = 0; cc < 5; ++cc) {
    __syncthreads();
    *(half8*)&Kc[kr_r0][kr_q * 8] = kr0;
    *(half8*)&Kc[kr_r1][kr_q * 8] = kr1;
    #pragma unroll
    for (int u = 0; u < 8; ++u) {
      int d = vd0 + u;
      Vtc[d][vj0 ^ (d & 56)] = vr0[u];
      Vtc[d][vj1 ^ (d & 56)] = vr1[u];
    }
    if (cc < 4) {
      const _Float16* kb = proj + (size_t)(jlo + (cc + 1) * 64) * PW + 1024 + hb;
      const _Float16* vb = proj + (size_t)(jlo + (cc + 1) * 64) * PW + 2048 + hb;
      kr0 = *(const half8*)(kb + (size_t)kr_r0 * PW + kr_q * 8);
      kr1 = *(const half8*)(kb + (size_t)kr_r1 * PW + kr_q * 8);
      vr0 = *(const half8*)(vb + (size_t)vj0 * PW + vd0);
      vr1 = *(const half8*)(vb + (size_t)vj1 * PW + vd0);
    }
    __syncthreads();

    float sc[4][4];
    #pragma unroll
    for (int cb = 0; cb < 4; ++cb) {
      half8 b0 = *(const half8*)&Kc[cb * 16 + l15][q4 * 8];
      half8 b1 = *(const half8*)&Kc[cb * 16 + l15][32 + q4 * 8];
      floatx4 a = (floatx4){0.f, 0.f, 0.f, 0.f};
      a = __builtin_amdgcn_mfma_f32_16x16x32_f16(qf0, b0, a, 0, 0, 0);
      a = __builtin_amdgcn_mfma_f32_16x16x32_f16(qf1, b1, a, 0, 0, 0);
      #pragma unroll
      for (int r = 0; r < 4; ++r) sc[cb][r] = a[r];
    }

    #pragma unroll
    for (int r = 0; r < 4; ++r) {
      int ri = w * 16 + q4 * 4 + r;
      float rowp = 0.f;
      #pragma unroll
      for (int cb = 0; cb < 4; ++cb) {
        int jjg = cc * 64 + cb * 16 + l15;
        bool valid = (jjg >= ri) && (jjg <= ri + 256);
        float p = valid ? __expf(sc[cb][r] * 0.125f) : 0.f;
        Ps[ri][cb * 16 + l15] = (_Float16)p;
        rowp += p;
      }
      lpart[r] += rowp;
    }

    half8 pf0 = *(const half8*)&Ps[w * 16 + l15][q4 * 8];
    half8 pf1 = *(const half8*)&Ps[w * 16 + l15][32 + q4 * 8];
    #pragma unroll
    for (int cb = 0; cb < 4; ++cb) {
      int dv = cb * 16 + l15;
      half8 v0 = *(const half8*)&Vtc[dv][(q4 * 8) ^ (dv & 56)];
      half8 v1 = *(const half8*)&Vtc[dv][(32 + q4 * 8) ^ (dv & 56)];
      oacc[cb] = __builtin_amdgcn_mfma_f32_16x16x32_f16(pf0, v0, oacc[cb], 0, 0, 0);
      oacc[cb] = __builtin_amdgcn_mfma_f32_16x16x32_f16(pf1, v1, oacc[cb], 0, 0, 0);
    }
  }

  #pragma unroll
  for (int r = 0; r < 4; ++r) {
    int ri = w * 16 + q4 * 4 + r;
    if (i0 + ri < 260) continue;
    float lsum = lpart[r];
    #pragma unroll
    for (int off = 1; off < 16; off <<= 1) lsum += __shfl_xor(lsum, off, 64);
    float inv = 1.f / (lsum + 4.f);   // +4: global cols 0..3 at score exactly 0
    #pragma unroll
    for (int cb = 0; cb < 4; ++cb) {
      int col = cb * 16 + l15;
      float ol = (oacc[cb][r] + svg_s[col]) * inv;
      float og = 0.f;
      #pragma unroll
      for (int g = 0; g < 4; ++g) og += pg_s[g][ri] * (float)vg_s[g][col];
      out[(size_t)(i0 + ri) * DMODEL + hb + col] = (_Float16)(ol + og);
    }
  }
}

// ---------------- launcher ----------------
extern "C" void kernel_launch(void* const* d_in, const int* in_sizes, int n_in,
                              void* d_out, int out_size, void* d_ws, size_t ws_size,
                              hipStream_t stream) {
  const float* x     = (const float*)d_in[0];
  const float* cos_t = (const float*)d_in[1];
  const float* sin_t = (const float*)d_in[2];
  const int*   pos   = (const int*)d_in[3];
  const float* Wqs   = (const float*)d_in[4];
  const float* Wks   = (const float*)d_in[5];
  const float* Wvs   = (const float*)d_in[6];
  const float* Wkg   = (const float*)d_in[8];
  const float* Wvg   = (const float*)d_in[9];
  const float* Wo    = (const float*)d_in[10];
  float* out = (float*)d_out;

  char* ws = (char*)d_ws;
  _Float16* xh   = (_Float16*)(ws);                 //  4 MB
  _Float16* wcat = (_Float16*)(ws + (4u << 20));    // 10 MB
  _Float16* wot  = (_Float16*)(ws + (14u << 20));   //  2 MB
  _Float16* proj = (_Float16*)(ws + (16u << 20));   // 20 MB
  _Float16* attn = (_Float16*)(ws + (36u << 20));   //  4 MB

  k_prep<<<2560, 256, 0, stream>>>(x, Wqs, Wks, Wvs, Wkg, Wvg, Wo, xh, wcat, wot);
  // sparse proj GEMM: 768 blocks q|k|v (all M) + 32 blocks kg|vg (m0=0 only), XCD-swizzled
  k_gemm<true, true, true, 128, 64><<<800, 256, 0, stream>>>(
      xh, wcat, proj, nullptr, cos_t, sin_t, pos, SEQ, PW, DMODEL);
  // attn: 28 flash tiles (64 rows) + 65 early blocks (4 rows), per head; 256 threads
  k_attn<<<dim3(93, NHEADS), 256, 0, stream>>>(proj, attn);
  // out GEMM: 64x64 tiles, 1D grid 512 (XCD-swizzled, n-major), fp32 direct to out
  k_gemm<false, false, false, 64, 64><<<512, 256, 0, stream>>>(
      attn, wot, nullptr, out, cos_t, sin_t, pos, SEQ, DMODEL, DMODEL);
}

// Round 9
// 153.036 us; speedup vs baseline: 1.0440x; 1.0274x over previous
//
#include <hip/hip_runtime.h>

typedef _Float16 half8 __attribute__((ext_vector_type(8)));
typedef float floatx4 __attribute__((ext_vector_type(4)));

#define SEQ 2048
#define DMODEL 1024
#define NHEADS 16
#define HEADDIM 64
#define PW 5120   // proj row width: q|k|v|kg|vg

// ---------------- fused prep: x fp32->fp16 + 6 weight transposes ----------------
__global__ __launch_bounds__(256) void k_prep(
    const float* __restrict__ x,
    const float* __restrict__ w0, const float* __restrict__ w1, const float* __restrict__ w2,
    const float* __restrict__ w3, const float* __restrict__ w4, const float* __restrict__ w5,
    _Float16* __restrict__ xh, _Float16* __restrict__ wcat, _Float16* __restrict__ wot) {
  const int tid = threadIdx.x;
  const int b = blockIdx.x;
  if (b < 1024) {
    int base = b * 2048 + tid * 8;
    floatx4 f0 = *(const floatx4*)(x + base);
    floatx4 f1 = *(const floatx4*)(x + base + 4);
    half8 h;
    #pragma unroll
    for (int e = 0; e < 4; ++e) { h[e] = (_Float16)f0[e]; h[e + 4] = (_Float16)f1[e]; }
    *(half8*)(xh + base) = h;
    return;
  }
  __shared__ _Float16 T[64][72];
  int t = b - 1024;
  int z = t >> 8;
  int tile = t & 255;
  int k0 = (tile >> 4) * 64, n0 = (tile & 15) * 64;
  const float* W = (z == 0) ? w0 : (z == 1) ? w1 : (z == 2) ? w2
                 : (z == 3) ? w3 : (z == 4) ? w4 : w5;
  _Float16* dst = (z < 5) ? (wcat + (size_t)z * 1024 * 1024) : wot;

  int lr = tid >> 2, c0 = (tid & 3) * 16;
  #pragma unroll
  for (int i = 0; i < 4; ++i) {
    floatx4 f = *(const floatx4*)(W + (size_t)(k0 + lr) * DMODEL + n0 + c0 + i * 4);
    #pragma unroll
    for (int e = 0; e < 4; ++e) T[c0 + i * 4 + e][lr] = (_Float16)f[e];
  }
  __syncthreads();
  int nr = tid >> 2, s0 = (tid & 3) * 16;
  #pragma unroll
  for (int i = 0; i < 2; ++i) {
    half8 h = *(const half8*)&T[nr][s0 + i * 8];
    *(half8*)(dst + (size_t)(n0 + nr) * DMODEL + k0 + s0 + i * 8) = h;
  }
}

// ------------- BMxBN MFMA GEMM, BK=128 1-phase, global_load_lds + XOR swizzle -------------
// R5 structure (best measured, 154.4 us): single-buffered, __syncthreads-delimited
// K-steps; latency hiding from multi-block co-residency (NOT source pipelining —
// R4's dbuf/counted-vmcnt regressed; NOT XCD swizzle — R8's swizzle regressed:
// working sets are L2/L3-resident, default dispatch locality already sufficient).
// BM=128,BN=64 (proj): wave grid 4x1, acc[2][4]; RoPE pairs (d,d+32) intra-wave.
//   48KB LDS -> 3 blocks/CU. Grid 800: 768 q|k|v + 32 kg|vg (m0=0 only).
// BM=64,BN=64 (out): wave grid 2x2, acc[2][2]; 32KB; grid 512 = exactly 2/CU so a
//   co-resident block's MFMA covers the other's stage-drain.
template <bool HALF_OUT, bool FUSE_ROPE, bool SPARSE, int BM, int BN>
__global__ __launch_bounds__(256, 3) void k_gemm(
    const _Float16* __restrict__ A, const _Float16* __restrict__ Bt,
    void* __restrict__ Cv, float* __restrict__ Cp,
    const float* __restrict__ cos_t, const float* __restrict__ sin_t,
    const int* __restrict__ pos, int M, int N, int K) {
  __shared__ _Float16 As[BM][128];
  __shared__ _Float16 Bs[BN][128];
  const int tid = threadIdx.x;
  const int lane = tid & 63;
  const int w = tid >> 6;
  const int l15 = lane & 15;
  const int q4 = lane >> 4;
  constexpr int NJ = (BM == 128) ? 4 : 2;           // col fragments per wave
  const int wm = (BM == 128) ? w * 32 : (w >> 1) * 32;
  const int wn = (BM == 128) ? 0 : (w & 1) * 32;
  int m0, n0;
  if (SPARSE) {
    int b = blockIdx.x;
    if (b < 768) { m0 = (b & 15) * 128; n0 = (b >> 4) * 64; }
    else         { m0 = 0;              n0 = 3072 + (b - 768) * 64; }
  } else {
    m0 = blockIdx.x * BM;
    n0 = blockIdx.y * BN;
  }

  floatx4 acc[2][NJ];
  #pragma unroll
  for (int i = 0; i < 2; ++i)
    #pragma unroll
    for (int j = 0; j < NJ; ++j) acc[i][j] = (floatx4){0.f, 0.f, 0.f, 0.f};

  _Float16* asBase = &As[0][0];
  _Float16* bsBase = &Bs[0][0];
  const int swz = l15 & 7;

  for (int k0 = 0; k0 < K; k0 += 128) {
    __syncthreads();
    #pragma unroll
    for (int it = 0; it < BM / 16; ++it) {
      int c = it * 256 + tid;          // A: 16B chunks, 16 chunks/row
      int r = c >> 4, cc = c & 15;
      int g = cc ^ (r & 7);            // swizzled global k-chunk
      __builtin_amdgcn_global_load_lds(
          (const __attribute__((address_space(1))) void*)(A + (size_t)(m0 + r) * K + k0 + g * 8),
          (__attribute__((address_space(3))) void*)(asBase + (it * 256 + w * 64) * 8),
          16, 0, 0);
    }
    #pragma unroll
    for (int it = 0; it < BN / 16; ++it) {
      int c = it * 256 + tid;          // B: 16B chunks
      int r = c >> 4, cc = c & 15;
      int g = cc ^ (r & 7);
      __builtin_amdgcn_global_load_lds(
          (const __attribute__((address_space(1))) void*)(Bt + (size_t)(n0 + r) * K + k0 + g * 8),
          (__attribute__((address_space(3))) void*)(bsBase + (it * 256 + w * 64) * 8),
          16, 0, 0);
    }
    __syncthreads();

    #pragma unroll
    for (int kk = 0; kk < 4; ++kk) {
      int q = kk * 4 + q4;             // global k-chunk 0..15
      half8 af[2], bf[NJ];
      #pragma unroll
      for (int t = 0; t < 2; ++t) {
        int ar = wm + t * 16 + l15;
        af[t] = *(const half8*)(asBase + (size_t)ar * 128 + ((q ^ swz) * 8));
      }
      #pragma unroll
      for (int t = 0; t < NJ; ++t) {
        int br = wn + t * 16 + l15;
        bf[t] = *(const half8*)(bsBase + (size_t)br * 128 + ((q ^ swz) * 8));
      }
      #pragma unroll
      for (int i = 0; i < 2; ++i)
        #pragma unroll
        for (int j = 0; j < NJ; ++j)
          acc[i][j] = __builtin_amdgcn_mfma_f32_16x16x32_f16(af[i], bf[j], acc[i][j], 0, 0, 0);
    }
  }

  #pragma unroll
  for (int tm = 0; tm < 2; ++tm) {
    #pragma unroll
    for (int r = 0; r < 4; ++r) {
      int row = m0 + wm + tm * 16 + q4 * 4 + r;
      float v[NJ];
      #pragma unroll
      for (int tn = 0; tn < NJ; ++tn) v[tn] = acc[tm][tn][r];
      if (FUSE_ROPE && NJ == 4 && n0 < 2048) {
        int p = pos[row];
        #pragma unroll
        for (int tn = 0; tn < 2; ++tn) {
          int d = tn * 16 + l15;       // head-local col (wave spans full head)
          float a = acc[tm][tn][r];
          float bvv = acc[tm][tn + 2][r];
          float c1 = cos_t[p * 64 + d],      s1 = sin_t[p * 64 + d];
          float c2 = cos_t[p * 64 + d + 32], s2 = sin_t[p * 64 + d + 32];
          v[tn]     = a * c1 - bvv * s1;
          v[tn + 2] = bvv * c2 + a * s2;
        }
      }
      #pragma unroll
      for (int tn = 0; tn < NJ; ++tn) {
        int col = n0 + wn + tn * 16 + l15;
        if (HALF_OUT)
          ((_Float16*)Cv)[(size_t)row * N + col] = (_Float16)v[tn];
        else
          Cp[(size_t)row * N + col] = v[tn];
      }
    }
  }
}

// ---------------- merged attention: BM=64 flash tiles + early rows ----------------
// Fixed softmax reference m == 0 (scores O(+-3); shift invariance -> exact), linear
// l-sum deferred to epilogue. T14 reg staging; Vtc XOR swizzle (col ^ (d&56)).
// BM=64/4-wave blocks (R7's BM=32 regressed: same 7 waves/CU but 2x staging traffic).
__global__ __launch_bounds__(256, 2) void k_attn(const _Float16* __restrict__ proj,
                                                 _Float16* __restrict__ out) {
  const int tid = threadIdx.x;
  const int hb = blockIdx.y * 64;

  if (blockIdx.x >= 28) {
    // ---- early rows (absorbed-1e9: uniform average over in-window global cols) ----
    const int i = (blockIdx.x - 28) * 4 + (tid >> 6);
    const int lane = tid & 63;
    const float scale = 0.125f;
    float qv = (float)proj[(size_t)i * PW + hb + lane];
    float sg[4];
    #pragma unroll
    for (int g = 0; g < 4; ++g) {
      float kgv = (float)proj[(size_t)g * PW + 3072 + hb + lane];
      float v = qv * kgv;
      #pragma unroll
      for (int off = 32; off; off >>= 1) v += __shfl_xor(v, off, 64);
      sg[g] = v * scale;
    }
    float mg = fmaxf(fmaxf(sg[0], sg[1]), fmaxf(sg[2], sg[3]));
    float dg = 0.f, og = 0.f;
    #pragma unroll
    for (int g = 0; g < 4; ++g) {
      float p = __expf(sg[g] - mg);
      dg += p;
      og += p * (float)proj[(size_t)g * PW + 4096 + hb + lane];
    }
    og /= dg;
    int jmin = (i >= 256) ? (i - 256) : 0;
    int jmax = (i < 3) ? i : 3;
    float acc = 0.f;
    for (int j = jmin; j <= jmax; ++j)
      acc += (float)proj[(size_t)j * PW + 2048 + hb + lane];
    float ol = acc / (float)(jmax - jmin + 1);
    out[(size_t)i * DMODEL + hb + lane] = (_Float16)(ol + og);
    return;
  }

  // ---- flash path: 64 Q-rows per block, 5 chunks of 64 cols ----
  const int i0 = 256 + blockIdx.x * 64;
  const int jlo = i0 - 256;
  const int lane = tid & 63;
  const int w = tid >> 6;
  const int l15 = lane & 15;
  const int q4 = lane >> 4;

  __shared__ _Float16 Qs[64][72];
  __shared__ _Float16 Kc[64][72];
  __shared__ _Float16 Vtc[64][72];
  __shared__ _Float16 Ps[64][72];
  __shared__ _Float16 kg_s[4][64];
  __shared__ _Float16 vg_s[4][64];
  __shared__ float svg_s[64];
  __shared__ float pg_s[4][64];

  #pragma unroll
  for (int rep = 0; rep < 2; ++rep) {
    int c = tid + rep * 256;
    int r = c >> 3, q = c & 7;
    *(half8*)&Qs[r][q * 8] = *(const half8*)(proj + (size_t)(i0 + r) * PW + hb + q * 8);
  }
  {
    int g = tid >> 6, c2 = tid & 63;
    kg_s[g][c2] = proj[(size_t)g * PW + 3072 + hb + c2];
    vg_s[g][c2] = proj[(size_t)g * PW + 4096 + hb + c2];
    if (tid < 64) {
      float s = 0.f;
      #pragma unroll
      for (int g2 = 0; g2 < 4; ++g2) s += (float)proj[(size_t)g2 * PW + 2048 + hb + tid];
      svg_s[tid] = s;
    }
  }
  __syncthreads();

  // global-attn probs for the 64 rows: (w, lane>>2) -> row, lane&3 -> k-part
  {
    int ro = w * 16 + (lane >> 2);
    int part = lane & 3;
    float sg[4];
    #pragma unroll
    for (int g = 0; g < 4; ++g) {
      float acc = 0.f;
      #pragma unroll
      for (int u = 0; u < 16; ++u)
        acc += (float)Qs[ro][part * 16 + u] * (float)kg_s[g][part * 16 + u];
      acc += __shfl_xor(acc, 1, 64);
      acc += __shfl_xor(acc, 2, 64);
      sg[g] = acc * 0.125f;
    }
    float mg = fmaxf(fmaxf(sg[0], sg[1]), fmaxf(sg[2], sg[3]));
    float dg = 0.f;
    #pragma unroll
    for (int g = 0; g < 4; ++g) dg += __expf(sg[g] - mg);
    pg_s[part][ro] = __expf(sg[part] - mg) / dg;
  }

  half8 qf0 = *(const half8*)&Qs[w * 16 + l15][q4 * 8];
  half8 qf1 = *(const half8*)&Qs[w * 16 + l15][32 + q4 * 8];

  float lpart[4];
  floatx4 oacc[4];
  #pragma unroll
  for (int cb = 0; cb < 4; ++cb) {
    oacc[cb] = (floatx4){0.f, 0.f, 0.f, 0.f};
    lpart[cb] = 0.f;
  }

  const int kr_r0 = tid >> 3, kr_q = tid & 7;
  const int kr_r1 = kr_r0 + 32;
  const int vj0 = (tid & 7) + ((tid >> 6) << 3);
  const int vj1 = vj0 + 32;
  const int vd0 = ((tid >> 3) & 7) * 8;

  half8 kr0, kr1, vr0, vr1;
  {
    const _Float16* kb = proj + (size_t)jlo * PW + 1024 + hb;
    const _Float16* vb = proj + (size_t)jlo * PW + 2048 + hb;
    kr0 = *(const half8*)(kb + (size_t)kr_r0 * PW + kr_q * 8);
    kr1 = *(const half8*)(kb + (size_t)kr_r1 * PW + kr_q * 8);
    vr0 = *(const half8*)(vb + (size_t)vj0 * PW + vd0);
    vr1 = *(const half8*)(vb + (size_t)vj1 * PW + vd0);
  }

  for (int cc = 0; cc < 5; ++cc) {
    __syncthreads();
    *(half8*)&Kc[kr_r0][kr_q * 8] = kr0;
    *(half8*)&Kc[kr_r1][kr_q * 8] = kr1;
    #pragma unroll
    for (int u = 0; u < 8; ++u) {
      int d = vd0 + u;
      Vtc[d][vj0 ^ (d & 56)] = vr0[u];
      Vtc[d][vj1 ^ (d & 56)] = vr1[u];
    }
    if (cc < 4) {
      const _Float16* kb = proj + (size_t)(jlo + (cc + 1) * 64) * PW + 1024 + hb;
      const _Float16* vb = proj + (size_t)(jlo + (cc + 1) * 64) * PW + 2048 + hb;
      kr0 = *(const half8*)(kb + (size_t)kr_r0 * PW + kr_q * 8);
      kr1 = *(const half8*)(kb + (size_t)kr_r1 * PW + kr_q * 8);
      vr0 = *(const half8*)(vb + (size_t)vj0 * PW + vd0);
      vr1 = *(const half8*)(vb + (size_t)vj1 * PW + vd0);
    }
    __syncthreads();

    float sc[4][4];
    #pragma unroll
    for (int cb = 0; cb < 4; ++cb) {
      half8 b0 = *(const half8*)&Kc[cb * 16 + l15][q4 * 8];
      half8 b1 = *(const half8*)&Kc[cb * 16 + l15][32 + q4 * 8];
      floatx4 a = (floatx4){0.f, 0.f, 0.f, 0.f};
      a = __builtin_amdgcn_mfma_f32_16x16x32_f16(qf0, b0, a, 0, 0, 0);
      a = __builtin_amdgcn_mfma_f32_16x16x32_f16(qf1, b1, a, 0, 0, 0);
      #pragma unroll
      for (int r = 0; r < 4; ++r) sc[cb][r] = a[r];
    }

    #pragma unroll
    for (int r = 0; r < 4; ++r) {
      int ri = w * 16 + q4 * 4 + r;
      float rowp = 0.f;
      #pragma unroll
      for (int cb = 0; cb < 4; ++cb) {
        int jjg = cc * 64 + cb * 16 + l15;
        bool valid = (jjg >= ri) && (jjg <= ri + 256);
        float p = valid ? __expf(sc[cb][r] * 0.125f) : 0.f;
        Ps[ri][cb * 16 + l15] = (_Float16)p;
        rowp += p;
      }
      lpart[r] += rowp;
    }

    half8 pf0 = *(const half8*)&Ps[w * 16 + l15][q4 * 8];
    half8 pf1 = *(const half8*)&Ps[w * 16 + l15][32 + q4 * 8];
    #pragma unroll
    for (int cb = 0; cb < 4; ++cb) {
      int dv = cb * 16 + l15;
      half8 v0 = *(const half8*)&Vtc[dv][(q4 * 8) ^ (dv & 56)];
      half8 v1 = *(const half8*)&Vtc[dv][(32 + q4 * 8) ^ (dv & 56)];
      oacc[cb] = __builtin_amdgcn_mfma_f32_16x16x32_f16(pf0, v0, oacc[cb], 0, 0, 0);
      oacc[cb] = __builtin_amdgcn_mfma_f32_16x16x32_f16(pf1, v1, oacc[cb], 0, 0, 0);
    }
  }

  #pragma unroll
  for (int r = 0; r < 4; ++r) {
    int ri = w * 16 + q4 * 4 + r;
    if (i0 + ri < 260) continue;
    float lsum = lpart[r];
    #pragma unroll
    for (int off = 1; off < 16; off <<= 1) lsum += __shfl_xor(lsum, off, 64);
    float inv = 1.f / (lsum + 4.f);   // +4: global cols 0..3 at score exactly 0
    #pragma unroll
    for (int cb = 0; cb < 4; ++cb) {
      int col = cb * 16 + l15;
      float ol = (oacc[cb][r] + svg_s[col]) * inv;
      float og = 0.f;
      #pragma unroll
      for (int g = 0; g < 4; ++g) og += pg_s[g][ri] * (float)vg_s[g][col];
      out[(size_t)(i0 + ri) * DMODEL + hb + col] = (_Float16)(ol + og);
    }
  }
}

// ---------------- launcher ----------------
extern "C" void kernel_launch(void* const* d_in, const int* in_sizes, int n_in,
                              void* d_out, int out_size, void* d_ws, size_t ws_size,
                              hipStream_t stream) {
  const float* x     = (const float*)d_in[0];
  const float* cos_t = (const float*)d_in[1];
  const float* sin_t = (const float*)d_in[2];
  const int*   pos   = (const int*)d_in[3];
  const float* Wqs   = (const float*)d_in[4];
  const float* Wks   = (const float*)d_in[5];
  const float* Wvs   = (const float*)d_in[6];
  const float* Wkg   = (const float*)d_in[8];
  const float* Wvg   = (const float*)d_in[9];
  const float* Wo    = (const float*)d_in[10];
  float* out = (float*)d_out;

  char* ws = (char*)d_ws;
  _Float16* xh   = (_Float16*)(ws);                 //  4 MB
  _Float16* wcat = (_Float16*)(ws + (4u << 20));    // 10 MB
  _Float16* wot  = (_Float16*)(ws + (14u << 20));   //  2 MB
  _Float16* proj = (_Float16*)(ws + (16u << 20));   // 20 MB
  _Float16* attn = (_Float16*)(ws + (36u << 20));   //  4 MB

  k_prep<<<2560, 256, 0, stream>>>(x, Wqs, Wks, Wvs, Wkg, Wvg, Wo, xh, wcat, wot);
  // sparse proj GEMM: 768 blocks q|k|v (all M) + 32 blocks kg|vg (m0=0 only)
  k_gemm<true, true, true, 128, 64><<<800, 256, 0, stream>>>(
      xh, wcat, proj, nullptr, cos_t, sin_t, pos, SEQ, PW, DMODEL);
  // attn: 28 flash tiles (64 rows) + 65 early blocks (4 rows), per head; 256 threads
  k_attn<<<dim3(93, NHEADS), 256, 0, stream>>>(proj, attn);
  // out GEMM: 64x64 tiles, 512 blocks = exactly 2/CU, fp32 direct to out
  k_gemm<false, false, false, 64, 64><<<dim3(32, 16), 256, 0, stream>>>(
      attn, wot, nullptr, out, cos_t, sin_t, pos, SEQ, DMODEL, DMODEL);
}